// Round 3
// 606.109 us; speedup vs baseline: 1.2012x; 1.2012x over previous
//
#include <hip/hip_runtime.h>
#include <hip/hip_bf16.h>

using u16 = unsigned short;
using u32 = unsigned int;
typedef __attribute__((ext_vector_type(8))) short short8;
typedef __attribute__((ext_vector_type(4))) float f32x4;

// ---------- helpers ----------
__device__ __forceinline__ float bf2f(u16 x){ return __uint_as_float(((u32)x)<<16); }
__device__ __forceinline__ u16 f2bf(float f){
  u32 u = __float_as_uint(f);
  u += 0x7fffu + ((u>>16)&1u);          // round-to-nearest-even
  return (u16)(u>>16);
}
__device__ __forceinline__ u32 cvtpk(float a, float b){
  u32 r;
  asm("v_cvt_pk_bf16_f32 %0, %1, %2" : "=v"(r) : "v"(a), "v"(b));
  return r;                              // lo16 = bf16(a), hi16 = bf16(b), RNE
}
__device__ __forceinline__ short8 pack8(float4 a, float4 b){
  union { short8 s; u32 u[4]; } r;
  r.u[0] = (u32)f2bf(a.x) | ((u32)f2bf(a.y)<<16);
  r.u[1] = (u32)f2bf(a.z) | ((u32)f2bf(a.w)<<16);
  r.u[2] = (u32)f2bf(b.x) | ((u32)f2bf(b.y)<<16);
  r.u[3] = (u32)f2bf(b.z) | ((u32)f2bf(b.w)<<16);
  return r.s;
}
#define MFMA(a,b,c) __builtin_amdgcn_mfma_f32_16x16x32_bf16((a),(b),(c),0,0,0)

// ws layout (u16 offsets): Wt_b 0, Wp_b 131072, Wg_b 262144, Wo_b 393216,
// Wm_b 524288, end 589824. ctxp at 589824. theta/phi/g follow.
// theta/phi are X-MAJOR per head: [n][h][x][16]; g stays d-major [n][c][x].
// yT aliases ctxp (dead after k_proj).

// ---------- K0: weights fp32 -> bf16 ----------
__global__ __launch_bounds__(256) void k_prep(
    const float* __restrict__ Wt, const float* __restrict__ Wp,
    const float* __restrict__ Wg, const float* __restrict__ Wo,
    const float* __restrict__ Wm, u16* __restrict__ wb)
{
  int i8 = (blockIdx.x*256 + threadIdx.x)*8;
  const float* src; int local;
  if      (i8 < 131072){ src = Wt; local = i8; }
  else if (i8 < 262144){ src = Wp; local = i8-131072; }
  else if (i8 < 393216){ src = Wg; local = i8-262144; }
  else if (i8 < 524288){ src = Wo; local = i8-393216; }
  else                 { src = Wm; local = i8-524288; }
  float4 a = *(const float4*)(src+local);
  float4 b = *(const float4*)(src+local+4);
  union { short8 s; uint4 u; } r;
  r.s = pack8(a,b);
  *(uint4*)(wb + i8) = r.u;
}

// ---------- K1: position mixing via MFMA ----------
__global__ __launch_bounds__(256) void k_posmix(
    const float* __restrict__ ctx, const u16* __restrict__ wm_b,
    const float* __restrict__ bm, u16* __restrict__ ctxp)
{
  int lane = threadIdx.x & 63;
  int l15 = lane & 15, q = lane >> 4;
  int wv = (blockIdx.x<<2) + (threadIdx.x>>6);     // 0..16383
  int n = wv >> 4, h = wv & 15;
  const float* cbase = ctx + (size_t)n*32768 + h*2048;   // ctx[n][h*32][0]
  const u16*  wmb   = wm_b + h*4096;
  const f32x4 Z = {0.f,0.f,0.f,0.f};
  f32x4 acc[2][4];
  #pragma unroll
  for (int mi=0;mi<2;mi++)
    #pragma unroll
    for (int ni=0;ni<4;ni++) acc[mi][ni] = Z;

  #pragma unroll
  for (int ks=0; ks<2; ks++){
    short8 a[2], b[4];
    #pragma unroll
    for (int mi=0; mi<2; mi++){
      const float* ap = cbase + (mi*16 + l15)*64 + ks*32 + q*8;
      float4 v0 = *(const float4*)ap;
      float4 v1 = *(const float4*)(ap+4);
      a[mi] = pack8(v0, v1);
    }
    #pragma unroll
    for (int ni=0; ni<4; ni++)
      b[ni] = *(const short8*)(wmb + (ni*16 + l15)*64 + ks*32 + q*8);
    #pragma unroll
    for (int mi=0;mi<2;mi++)
      #pragma unroll
      for (int ni=0;ni<4;ni++) acc[mi][ni] = MFMA(a[mi], b[ni], acc[mi][ni]);
  }

  float bmv[4];
  #pragma unroll
  for (int ni=0;ni<4;ni++) bmv[ni] = bm[h*64 + ni*16 + l15];
  u16* obase = ctxp + (size_t)n*32768 + h*2048;
  #pragma unroll
  for (int mi=0;mi<2;mi++)
    #pragma unroll
    for (int r=0;r<4;r++){
      int row = mi*16 + q*4 + r;                   // d in [0,32)
      #pragma unroll
      for (int ni=0;ni<4;ni++){
        int col = ni*16 + l15;
        float res = cbase[row*64 + col];
        obase[row*64 + col] = f2bf(acc[mi][ni][r] + bmv[ni] + res);
      }
    }
}

// ---------- K2: theta/phi/g projections via MFMA ----------
// block = (n, tensor). K=512, staged per 32-K slice into LDS transposed.
// tensor==2 (g):      C[o x] = W x S          -> g[n][o][x]   (d-major)
// tensor==0/1 (th/ph): C[x o] = S^T x W^T     -> T[n][h][x][d] (x-major)
// A/B fragment layouts for 16x16x32 are the same lane mapping, so the
// loads are identical; only the MFMA operand order + epilogue change.
__global__ __launch_bounds__(256) void k_proj(
    const float* __restrict__ query, const u16* __restrict__ ctxp,
    const u16* __restrict__ wb, const float* __restrict__ bt,
    const float* __restrict__ bp, const float* __restrict__ bg,
    u16* __restrict__ theta, u16* __restrict__ phi, u16* __restrict__ g)
{
  __shared__ __align__(16) u16 sb[64*44 + 16];
  int t = threadIdx.x;
  int lane = t & 63, l15 = lane & 15, q = lane >> 4, w = t >> 6;
  int n = blockIdx.x, tensor = blockIdx.y;
  const u16* W = wb + tensor*131072;
  const float* bias = (tensor==0) ? bt : (tensor==1) ? bp : bg;
  u16* dst = (tensor==0) ? theta : (tensor==1) ? phi : g;
  bool sw = (tensor < 2);          // swapped orientation for theta/phi

  const f32x4 Z = {0.f,0.f,0.f,0.f};
  f32x4 acc[4][4];
  #pragma unroll
  for (int mi=0;mi<4;mi++)
    #pragma unroll
    for (int ni=0;ni<4;ni++) acc[mi][ni] = Z;

  int sc = (t>>4)*2;          // c-pair base (0..30)
  int sx = (t&15)*4;          // x base (0..60)

  for (int ks=0; ks<16; ks++){
    int k0 = ks*32;
    // ---- stage S[k0..k0+32)[0..64) -> sb[x*44 + kc] (bf16, transposed) ----
    if (tensor == 0){
      const float* s0 = query + (size_t)n*32768 + (size_t)(k0+sc)*64 + sx;
      float4 va = *(const float4*)s0;
      float4 vb = *(const float4*)(s0 + 64);
      *(u32*)&sb[(sx+0)*44 + sc] = (u32)f2bf(va.x) | ((u32)f2bf(vb.x)<<16);
      *(u32*)&sb[(sx+1)*44 + sc] = (u32)f2bf(va.y) | ((u32)f2bf(vb.y)<<16);
      *(u32*)&sb[(sx+2)*44 + sc] = (u32)f2bf(va.z) | ((u32)f2bf(vb.z)<<16);
      *(u32*)&sb[(sx+3)*44 + sc] = (u32)f2bf(va.w) | ((u32)f2bf(vb.w)<<16);
    } else {
      const u16* s0 = ctxp + (size_t)n*32768 + (size_t)(k0+sc)*64 + sx;
      uint2 ua = *(const uint2*)s0;
      uint2 ub = *(const uint2*)(s0 + 64);
      *(u32*)&sb[(sx+0)*44 + sc] = (ua.x & 0xffffu) | ((ub.x & 0xffffu)<<16);
      *(u32*)&sb[(sx+1)*44 + sc] = (ua.x >> 16)     | (ub.x & 0xffff0000u);
      *(u32*)&sb[(sx+2)*44 + sc] = (ua.y & 0xffffu) | ((ub.y & 0xffffu)<<16);
      *(u32*)&sb[(sx+3)*44 + sc] = (ua.y >> 16)     | (ub.y & 0xffff0000u);
    }
    __syncthreads();
    // ---- compute ----
    short8 wf[4], sf[4];
    #pragma unroll
    for (int mi=0;mi<4;mi++)
      wf[mi] = *(const short8*)(W + (size_t)(w*64 + mi*16 + l15)*512 + k0 + q*8);
    #pragma unroll
    for (int ni=0;ni<4;ni++){
      union { short8 s; uint2 u[2]; } bb;
      int bidx = (ni*16 + l15)*44 + q*8;
      bb.u[0] = *(const uint2*)&sb[bidx];
      bb.u[1] = *(const uint2*)&sb[bidx + 4];
      sf[ni] = bb.s;
    }
    if (sw){
      #pragma unroll
      for (int mi=0;mi<4;mi++)
        #pragma unroll
        for (int ni=0;ni<4;ni++) acc[mi][ni] = MFMA(sf[mi], wf[ni], acc[mi][ni]);
    } else {
      #pragma unroll
      for (int mi=0;mi<4;mi++)
        #pragma unroll
        for (int ni=0;ni<4;ni++) acc[mi][ni] = MFMA(wf[mi], sf[ni], acc[mi][ni]);
    }
    __syncthreads();
  }

  if (!sw){
    // g: rows = o channel, cols = x
    u16* dbase = dst + (size_t)n*16384;
    #pragma unroll
    for (int mi=0;mi<4;mi++)
      #pragma unroll
      for (int r=0;r<4;r++){
        int row = w*64 + mi*16 + q*4 + r;
        float bv = bias[row];
        #pragma unroll
        for (int ni=0;ni<4;ni++){
          int col = ni*16 + l15;
          dbase[row*64 + col] = f2bf(acc[mi][ni][r] + bv);
        }
      }
  } else {
    // theta/phi: acc[i][j][r]: row x = i*16+q*4+r, col o = w*64+j*16+l15
    // -> T[n][h = w*4+j][x][d = l15]
    u16* dbase = dst + (size_t)n*16384 + (size_t)w*4096;
    float bv[4];
    #pragma unroll
    for (int j=0;j<4;j++) bv[j] = bias[w*64 + j*16 + l15];
    #pragma unroll
    for (int i=0;i<4;i++)
      #pragma unroll
      for (int r=0;r<4;r++){
        int x = i*16 + q*4 + r;
        #pragma unroll
        for (int j=0;j<4;j++)
          dbase[j*1024 + x*16 + l15] = f2bf(acc[i][j][r] + bv[j]);
      }
  }
}

// ---------- K3: attention via MFMA (per n,head per wave) ----------
// S^T[k][q] = Phi^T(64k x 16d) x Theta(16d x 64q), K padded 16->32.
// C layout: col q = lane&15 (per 16-q tile), row k = (lane>>4)*4+reg.
// Softmax over k: 16 in-lane values + shfl_xor(16,32) butterfly; 1/sum
// stays in-register (PV output column is also lane&15).
// P bounced through per-wave 8KB LDS ([q][64k] bf16, 16B XOR swizzle)
// to re-fragment as PV's B operand. Y = g(16d x 64k) x P(64k x 64q).
__global__ __launch_bounds__(256) void k_attn(
    const u16* __restrict__ thetaT, const u16* __restrict__ phiT,
    const u16* __restrict__ g, u16* __restrict__ yT)
{
  __shared__ __align__(16) u16 pbuf[4][4096];     // per-wave 8KB P tile
  int lane = threadIdx.x & 63;
  int w = threadIdx.x >> 6;
  int wv = (blockIdx.x<<2) + w;                   // 0..16383
  int n = wv >> 4, h = wv & 15;
  int l15 = lane & 15, grp = lane >> 4;

  const u16* thB = thetaT + (size_t)n*16384 + h*1024;  // [x][16]
  const u16* phB = phiT   + (size_t)n*16384 + h*1024;  // [x][16]
  const u16* gB  = g      + (size_t)n*16384 + h*1024;  // [16][64] d-major

  const f32x4 Z = {0.f,0.f,0.f,0.f};

  // ---- QK^T ----
  short8 zz; { union{ short8 s; u32 u[4]; } z; z.u[0]=z.u[1]=z.u[2]=z.u[3]=0; zz=z.s; }
  bool real = grp < 2;                            // K-halves 16..31 are zero pad
  short8 aF[4], bF[4];
  #pragma unroll
  for (int kt=0;kt<4;kt++)
    aF[kt] = real ? *(const short8*)(phB + (kt*16+l15)*16 + grp*8) : zz;
  #pragma unroll
  for (int qt=0;qt<4;qt++)
    bF[qt] = real ? *(const short8*)(thB + (qt*16+l15)*16 + grp*8) : zz;

  f32x4 s[4][4];                                  // s[qt][kt]
  #pragma unroll
  for (int qt=0;qt<4;qt++)
    #pragma unroll
    for (int kt=0;kt<4;kt++)
      s[qt][kt] = MFMA(aF[kt], bF[qt], Z);

  // ---- softmax (over k) + pack P -> LDS ----
  char* pl = (char*)pbuf[w];
  float inv[4];
  #pragma unroll
  for (int qt=0;qt<4;qt++){
    float m = s[qt][0][0];
    #pragma unroll
    for (int kt=0;kt<4;kt++)
      m = fmaxf(m, fmaxf(fmaxf(s[qt][kt][0], s[qt][kt][1]),
                         fmaxf(s[qt][kt][2], s[qt][kt][3])));
    m = fmaxf(m, __shfl_xor(m, 16));
    m = fmaxf(m, __shfl_xor(m, 32));
    float sum = 0.f;
    #pragma unroll
    for (int kt=0;kt<4;kt++)
      #pragma unroll
      for (int r=0;r<4;r++){
        float p = __expf((s[qt][kt][r] - m)*0.25f);   // scores / sqrt(16)
        s[qt][kt][r] = p;
        sum += p;
      }
    sum += __shfl_xor(sum, 16);
    sum += __shfl_xor(sum, 32);
    inv[qt] = 1.f / sum;
    int qq = qt*16 + l15;
    int swz = (qq & 7) << 4;
    #pragma unroll
    for (int kt=0;kt<4;kt++){
      u32 lo = cvtpk(s[qt][kt][0], s[qt][kt][1]);
      u32 hi = cvtpk(s[qt][kt][2], s[qt][kt][3]);
      *(uint2*)(pl + qq*128 + ((kt*32 + grp*8) ^ swz)) = make_uint2(lo, hi);
    }
  }

  // ---- PV ----
  short8 ga[2];
  #pragma unroll
  for (int ks=0;ks<2;ks++)
    ga[ks] = *(const short8*)(gB + l15*64 + ks*32 + grp*8);  // A[d][k]

  u16* yb = yT + (size_t)n*16384 + (size_t)h*16 + grp*4;
  #pragma unroll
  for (int Q=0;Q<4;Q++){
    int qq = Q*16 + l15;
    int swz = (qq & 7) << 4;
    f32x4 acc = Z;
    #pragma unroll
    for (int ks=0;ks<2;ks++){
      short8 pb = *(const short8*)(pl + qq*128 + ((ks*64 + grp*16) ^ swz));
      acc = MFMA(ga[ks], pb, acc);                // D[d][q]
    }
    float iv = inv[Q];
    u32 o0 = cvtpk(acc[0]*iv, acc[1]*iv);
    u32 o1 = cvtpk(acc[2]*iv, acc[3]*iv);
    *(uint2*)(yb + (size_t)qq*256) = make_uint2(o0, o1);     // yT[n][q][h*16+d]
  }
}

// ---------- K4: out = Wo @ y + bo + query via MFMA ----------
__global__ __launch_bounds__(256) void k_out(
    const float* __restrict__ query, const u16* __restrict__ yT,
    const u16* __restrict__ wo_b, const float* __restrict__ bo,
    float* __restrict__ out)
{
  int t = threadIdx.x, lane = t & 63, l15 = lane & 15, q = lane >> 4, w = t >> 6;
  int n = blockIdx.x;
  int mbase = blockIdx.y*256 + w*64;
  const f32x4 Z = {0.f,0.f,0.f,0.f};
  f32x4 acc[4][4];
  #pragma unroll
  for (int mi=0;mi<4;mi++)
    #pragma unroll
    for (int ni=0;ni<4;ni++) acc[mi][ni] = Z;

  #pragma unroll 2
  for (int ks=0; ks<8; ks++){
    int k0 = ks*32;
    short8 a[4], b[4];
    #pragma unroll
    for (int mi=0;mi<4;mi++)
      a[mi] = *(const short8*)(wo_b + (size_t)(mbase + mi*16 + l15)*256 + k0 + q*8);
    #pragma unroll
    for (int ni=0;ni<4;ni++)
      b[ni] = *(const short8*)(yT + (size_t)n*16384 + (size_t)(ni*16 + l15)*256 + k0 + q*8);
    #pragma unroll
    for (int mi=0;mi<4;mi++)
      #pragma unroll
      for (int ni=0;ni<4;ni++) acc[mi][ni] = MFMA(a[mi], b[ni], acc[mi][ni]);
  }

  #pragma unroll
  for (int mi=0;mi<4;mi++)
    #pragma unroll
    for (int r=0;r<4;r++){
      int row = mbase + mi*16 + q*4 + r;
      float bv = bo[row];
      #pragma unroll
      for (int ni=0;ni<4;ni++){
        int col = ni*16 + l15;
        size_t idx = (size_t)n*32768 + (size_t)row*64 + col;
        out[idx] = acc[mi][ni][r] + bv + query[idx];
      }
    }
}

// ---------- launch ----------
extern "C" void kernel_launch(void* const* d_in, const int* in_sizes, int n_in,
                              void* d_out, int out_size, void* d_ws, size_t ws_size,
                              hipStream_t stream)
{
  const float* query = (const float*)d_in[0];
  const float* ctx   = (const float*)d_in[1];
  const float* Wm    = (const float*)d_in[2];
  const float* bm    = (const float*)d_in[3];
  const float* Wg    = (const float*)d_in[4];
  const float* bg    = (const float*)d_in[5];
  const float* Wt    = (const float*)d_in[6];
  const float* bt    = (const float*)d_in[7];
  const float* Wp    = (const float*)d_in[8];
  const float* bp    = (const float*)d_in[9];
  const float* Wo    = (const float*)d_in[10];
  const float* bo    = (const float*)d_in[11];

  u16* wb    = (u16*)d_ws;                 // bf16 weights: 589824 u16
  u16* ctxp  = wb + 589824;                // [1024][512][64] bf16
  u16* theta = ctxp + 33554432;            // [1024][16][64][16] bf16 (x-major)
  u16* phi   = theta + 16777216;           // [1024][16][64][16] bf16 (x-major)
  u16* g     = phi + 16777216;             // [1024][256][64] bf16 (d-major)
  u16* yTb   = ctxp;                       // alias: ctxp dead after k_proj
  float* outp = (float*)d_out;

  hipLaunchKernelGGL(k_prep,   dim3(288),     dim3(256), 0, stream, Wt,Wp,Wg,Wo,Wm, wb);
  hipLaunchKernelGGL(k_posmix, dim3(4096),    dim3(256), 0, stream, ctx, wb+524288, bm, ctxp);
  hipLaunchKernelGGL(k_proj,   dim3(1024,3),  dim3(256), 0, stream,
                     query, ctxp, wb, bt, bp, bg, theta, phi, g);
  hipLaunchKernelGGL(k_attn,   dim3(4096),    dim3(256), 0, stream, theta, phi, g, yTb);
  hipLaunchKernelGGL(k_out,    dim3(1024,2),  dim3(256), 0, stream, query, yTb, wb+393216, bo, outp);
}

// Round 4
// 581.289 us; speedup vs baseline: 1.2525x; 1.0427x over previous
//
#include <hip/hip_runtime.h>
#include <hip/hip_bf16.h>

using u16 = unsigned short;
using u32 = unsigned int;
typedef __attribute__((ext_vector_type(8))) short short8;
typedef __attribute__((ext_vector_type(4))) float f32x4;

// ---------- helpers ----------
__device__ __forceinline__ float bf2f(u16 x){ return __uint_as_float(((u32)x)<<16); }
__device__ __forceinline__ u16 f2bf(float f){
  u32 u = __float_as_uint(f);
  u += 0x7fffu + ((u>>16)&1u);          // round-to-nearest-even
  return (u16)(u>>16);
}
__device__ __forceinline__ u32 cvtpk(float a, float b){
  u32 r;
  asm("v_cvt_pk_bf16_f32 %0, %1, %2" : "=v"(r) : "v"(a), "v"(b));
  return r;                              // lo16 = bf16(a), hi16 = bf16(b), RNE
}
__device__ __forceinline__ short8 pack8(float4 a, float4 b){
  union { short8 s; u32 u[4]; } r;
  r.u[0] = (u32)f2bf(a.x) | ((u32)f2bf(a.y)<<16);
  r.u[1] = (u32)f2bf(a.z) | ((u32)f2bf(a.w)<<16);
  r.u[2] = (u32)f2bf(b.x) | ((u32)f2bf(b.y)<<16);
  r.u[3] = (u32)f2bf(b.z) | ((u32)f2bf(b.w)<<16);
  return r.s;
}
#define MFMA(a,b,c) __builtin_amdgcn_mfma_f32_16x16x32_bf16((a),(b),(c),0,0,0)

// ws layout (u16 offsets): Wt_b 0, Wp_b 131072, Wg_b 262144, Wo_b 393216,
// Wm_b 524288, end 589824. ctxp at 589824. theta/phi/g follow.
// theta/phi are X-MAJOR per head: [n][h][x][16]; g stays d-major [n][c][x].
// yT aliases ctxp (dead after k_proj).

// ---------- K0: weights fp32 -> bf16 ----------
__global__ __launch_bounds__(256) void k_prep(
    const float* __restrict__ Wt, const float* __restrict__ Wp,
    const float* __restrict__ Wg, const float* __restrict__ Wo,
    const float* __restrict__ Wm, u16* __restrict__ wb)
{
  int i8 = (blockIdx.x*256 + threadIdx.x)*8;
  const float* src; int local;
  if      (i8 < 131072){ src = Wt; local = i8; }
  else if (i8 < 262144){ src = Wp; local = i8-131072; }
  else if (i8 < 393216){ src = Wg; local = i8-262144; }
  else if (i8 < 524288){ src = Wo; local = i8-393216; }
  else                 { src = Wm; local = i8-524288; }
  float4 a = *(const float4*)(src+local);
  float4 b = *(const float4*)(src+local+4);
  union { short8 s; uint4 u; } r;
  r.s = pack8(a,b);
  *(uint4*)(wb + i8) = r.u;
}

// ---------- K1: position mixing via MFMA ----------
__global__ __launch_bounds__(256) void k_posmix(
    const float* __restrict__ ctx, const u16* __restrict__ wm_b,
    const float* __restrict__ bm, u16* __restrict__ ctxp)
{
  int lane = threadIdx.x & 63;
  int l15 = lane & 15, q = lane >> 4;
  int wv = (blockIdx.x<<2) + (threadIdx.x>>6);     // 0..16383
  int n = wv >> 4, h = wv & 15;
  const float* cbase = ctx + (size_t)n*32768 + h*2048;   // ctx[n][h*32][0]
  const u16*  wmb   = wm_b + h*4096;
  const f32x4 Z = {0.f,0.f,0.f,0.f};
  f32x4 acc[2][4];
  #pragma unroll
  for (int mi=0;mi<2;mi++)
    #pragma unroll
    for (int ni=0;ni<4;ni++) acc[mi][ni] = Z;

  #pragma unroll
  for (int ks=0; ks<2; ks++){
    short8 a[2], b[4];
    #pragma unroll
    for (int mi=0; mi<2; mi++){
      const float* ap = cbase + (mi*16 + l15)*64 + ks*32 + q*8;
      float4 v0 = *(const float4*)ap;
      float4 v1 = *(const float4*)(ap+4);
      a[mi] = pack8(v0, v1);
    }
    #pragma unroll
    for (int ni=0; ni<4; ni++)
      b[ni] = *(const short8*)(wmb + (ni*16 + l15)*64 + ks*32 + q*8);
    #pragma unroll
    for (int mi=0;mi<2;mi++)
      #pragma unroll
      for (int ni=0;ni<4;ni++) acc[mi][ni] = MFMA(a[mi], b[ni], acc[mi][ni]);
  }

  float bmv[4];
  #pragma unroll
  for (int ni=0;ni<4;ni++) bmv[ni] = bm[h*64 + ni*16 + l15];
  u16* obase = ctxp + (size_t)n*32768 + h*2048;
  #pragma unroll
  for (int mi=0;mi<2;mi++)
    #pragma unroll
    for (int r=0;r<4;r++){
      int row = mi*16 + q*4 + r;                   // d in [0,32)
      #pragma unroll
      for (int ni=0;ni<4;ni++){
        int col = ni*16 + l15;
        float res = cbase[row*64 + col];
        obase[row*64 + col] = f2bf(acc[mi][ni][r] + bmv[ni] + res);
      }
    }
}

// ---------- K2: theta/phi/g projections via MFMA (pipelined) ----------
// block = (n, tensor). K=512 in 16x32-K steps, double-buffered LDS,
// ONE barrier per step. Per step: issue next staging+weight loads ->
// compute current (ds_read + 16 MFMA, weights prefetched last iter) ->
// convert+write next buffer -> barrier. Loads' latency hides under MFMA;
// the compiler's vmcnt(0)-at-barrier drain lands after consumption.
// tensor==2 (g):      C[o x] = W x S          -> g[n][o][x]   (d-major)
// tensor==0/1 (th/ph): C[x o] = S^T x W^T     -> T[n][h][x][d] (x-major)
__global__ __launch_bounds__(256) void k_proj(
    const float* __restrict__ query, const u16* __restrict__ ctxp,
    const u16* __restrict__ wb, const float* __restrict__ bt,
    const float* __restrict__ bp, const float* __restrict__ bg,
    u16* __restrict__ theta, u16* __restrict__ phi, u16* __restrict__ g)
{
  __shared__ __align__(16) u16 sb[2][64*44 + 16];
  int t = threadIdx.x;
  int lane = t & 63, l15 = lane & 15, q = lane >> 4, w = t >> 6;
  int n = blockIdx.x, tensor = blockIdx.y;
  const u16* W = wb + tensor*131072;
  const float* bias = (tensor==0) ? bt : (tensor==1) ? bp : bg;
  u16* dst = (tensor==0) ? theta : (tensor==1) ? phi : g;
  bool sw = (tensor < 2);          // swapped orientation for theta/phi

  const f32x4 Z = {0.f,0.f,0.f,0.f};
  f32x4 acc[4][4];
  #pragma unroll
  for (int mi=0;mi<4;mi++)
    #pragma unroll
    for (int ni=0;ni<4;ni++) acc[mi][ni] = Z;

  int sc = (t>>4)*2;          // c-pair base (0..30)
  int sx = (t&15)*4;          // x base (0..60)

  const float* qsrc = query + (size_t)n*32768 + (size_t)sc*64 + sx;
  const u16*  csrc = ctxp  + (size_t)n*32768 + (size_t)sc*64 + sx;

  // ---- prologue: stage ks=0 into sb[0] ----
  {
    u16* sbn = sb[0];
    if (tensor == 0){
      float4 va = *(const float4*)qsrc;
      float4 vb = *(const float4*)(qsrc + 64);
      *(u32*)&sbn[(sx+0)*44 + sc] = (u32)f2bf(va.x) | ((u32)f2bf(vb.x)<<16);
      *(u32*)&sbn[(sx+1)*44 + sc] = (u32)f2bf(va.y) | ((u32)f2bf(vb.y)<<16);
      *(u32*)&sbn[(sx+2)*44 + sc] = (u32)f2bf(va.z) | ((u32)f2bf(vb.z)<<16);
      *(u32*)&sbn[(sx+3)*44 + sc] = (u32)f2bf(va.w) | ((u32)f2bf(vb.w)<<16);
    } else {
      uint2 ua = *(const uint2*)csrc;
      uint2 ub = *(const uint2*)(csrc + 64);
      *(u32*)&sbn[(sx+0)*44 + sc] = (ua.x & 0xffffu) | ((ub.x & 0xffffu)<<16);
      *(u32*)&sbn[(sx+1)*44 + sc] = (ua.x >> 16)     | (ub.x & 0xffff0000u);
      *(u32*)&sbn[(sx+2)*44 + sc] = (ua.y & 0xffffu) | ((ub.y & 0xffffu)<<16);
      *(u32*)&sbn[(sx+3)*44 + sc] = (ua.y >> 16)     | (ub.y & 0xffff0000u);
    }
  }
  // weights for ks=0 (latency covered by stage+barrier)
  short8 wf[4];
  #pragma unroll
  for (int mi=0;mi<4;mi++)
    wf[mi] = *(const short8*)(W + (size_t)(w*64 + mi*16 + l15)*512 + q*8);
  __syncthreads();

  #pragma unroll 2
  for (int ks=0; ks<16; ks++){
    const u16* sbc = sb[ks&1];
    u16* sbn = sb[(ks+1)&1];
    int k0 = ks*32;
    bool more = (ks < 15);

    // ---- issue next-iter loads (consumed after the MFMAs) ----
    float4 pva, pvb; uint2 pua, pub;
    if (more){
      if (tensor == 0){
        const float* s0 = qsrc + (size_t)(k0+32)*64;
        pva = *(const float4*)s0;
        pvb = *(const float4*)(s0 + 64);
      } else {
        const u16* s0 = csrc + (size_t)(k0+32)*64;
        pua = *(const uint2*)s0;
        pub = *(const uint2*)(s0 + 64);
      }
    }
    short8 wn[4];
    if (more){
      #pragma unroll
      for (int mi=0;mi<4;mi++)
        wn[mi] = *(const short8*)(W + (size_t)(w*64 + mi*16 + l15)*512 + k0+32 + q*8);
    }

    // ---- compute current ----
    short8 sf[4];
    #pragma unroll
    for (int ni=0;ni<4;ni++){
      union { short8 s; uint2 u[2]; } bb;
      int bidx = (ni*16 + l15)*44 + q*8;
      bb.u[0] = *(const uint2*)&sbc[bidx];
      bb.u[1] = *(const uint2*)&sbc[bidx + 4];
      sf[ni] = bb.s;
    }
    if (sw){
      #pragma unroll
      for (int mi=0;mi<4;mi++)
        #pragma unroll
        for (int ni=0;ni<4;ni++) acc[mi][ni] = MFMA(sf[mi], wf[ni], acc[mi][ni]);
    } else {
      #pragma unroll
      for (int mi=0;mi<4;mi++)
        #pragma unroll
        for (int ni=0;ni<4;ni++) acc[mi][ni] = MFMA(wf[mi], sf[ni], acc[mi][ni]);
    }

    // ---- write next buffer + single barrier ----
    if (more){
      if (tensor == 0){
        *(u32*)&sbn[(sx+0)*44 + sc] = (u32)f2bf(pva.x) | ((u32)f2bf(pvb.x)<<16);
        *(u32*)&sbn[(sx+1)*44 + sc] = (u32)f2bf(pva.y) | ((u32)f2bf(pvb.y)<<16);
        *(u32*)&sbn[(sx+2)*44 + sc] = (u32)f2bf(pva.z) | ((u32)f2bf(pvb.z)<<16);
        *(u32*)&sbn[(sx+3)*44 + sc] = (u32)f2bf(pva.w) | ((u32)f2bf(pvb.w)<<16);
      } else {
        *(u32*)&sbn[(sx+0)*44 + sc] = (pua.x & 0xffffu) | ((pub.x & 0xffffu)<<16);
        *(u32*)&sbn[(sx+1)*44 + sc] = (pua.x >> 16)     | (pub.x & 0xffff0000u);
        *(u32*)&sbn[(sx+2)*44 + sc] = (pua.y & 0xffffu) | ((pub.y & 0xffffu)<<16);
        *(u32*)&sbn[(sx+3)*44 + sc] = (pua.y >> 16)     | (pub.y & 0xffff0000u);
      }
      __syncthreads();
      #pragma unroll
      for (int mi=0;mi<4;mi++) wf[mi] = wn[mi];
    }
  }

  if (!sw){
    // g: rows = o channel, cols = x
    u16* dbase = dst + (size_t)n*16384;
    #pragma unroll
    for (int mi=0;mi<4;mi++)
      #pragma unroll
      for (int r=0;r<4;r++){
        int row = w*64 + mi*16 + q*4 + r;
        float bv = bias[row];
        #pragma unroll
        for (int ni=0;ni<4;ni++){
          int col = ni*16 + l15;
          dbase[row*64 + col] = f2bf(acc[mi][ni][r] + bv);
        }
      }
  } else {
    // theta/phi: acc[i][j][r]: row x = i*16+q*4+r, col o = w*64+j*16+l15
    // -> T[n][h = w*4+j][x][d = l15]
    u16* dbase = dst + (size_t)n*16384 + (size_t)w*4096;
    float bv[4];
    #pragma unroll
    for (int j=0;j<4;j++) bv[j] = bias[w*64 + j*16 + l15];
    #pragma unroll
    for (int i=0;i<4;i++)
      #pragma unroll
      for (int r=0;r<4;r++){
        int x = i*16 + q*4 + r;
        #pragma unroll
        for (int j=0;j<4;j++)
          dbase[j*1024 + x*16 + l15] = f2bf(acc[i][j][r] + bv[j]);
      }
  }
}

// ---------- K3: attention via MFMA (per n,head per wave) ----------
__global__ __launch_bounds__(256) void k_attn(
    const u16* __restrict__ thetaT, const u16* __restrict__ phiT,
    const u16* __restrict__ g, u16* __restrict__ yT)
{
  __shared__ __align__(16) u16 pbuf[4][4096];     // per-wave 8KB P tile
  int lane = threadIdx.x & 63;
  int w = threadIdx.x >> 6;
  int wv = (blockIdx.x<<2) + w;                   // 0..16383
  int n = wv >> 4, h = wv & 15;
  int l15 = lane & 15, grp = lane >> 4;

  const u16* thB = thetaT + (size_t)n*16384 + h*1024;  // [x][16]
  const u16* phB = phiT   + (size_t)n*16384 + h*1024;  // [x][16]
  const u16* gB  = g      + (size_t)n*16384 + h*1024;  // [16][64] d-major

  const f32x4 Z = {0.f,0.f,0.f,0.f};

  // ---- QK^T ----
  short8 zz; { union{ short8 s; u32 u[4]; } z; z.u[0]=z.u[1]=z.u[2]=z.u[3]=0; zz=z.s; }
  bool real = grp < 2;                            // K-halves 16..31 are zero pad
  short8 aF[4], bF[4];
  #pragma unroll
  for (int kt=0;kt<4;kt++)
    aF[kt] = real ? *(const short8*)(phB + (kt*16+l15)*16 + grp*8) : zz;
  #pragma unroll
  for (int qt=0;qt<4;qt++)
    bF[qt] = real ? *(const short8*)(thB + (qt*16+l15)*16 + grp*8) : zz;

  f32x4 s[4][4];                                  // s[qt][kt]
  #pragma unroll
  for (int qt=0;qt<4;qt++)
    #pragma unroll
    for (int kt=0;kt<4;kt++)
      s[qt][kt] = MFMA(aF[kt], bF[qt], Z);

  // ---- softmax (over k) + pack P -> LDS ----
  char* pl = (char*)pbuf[w];
  float inv[4];
  #pragma unroll
  for (int qt=0;qt<4;qt++){
    float m = s[qt][0][0];
    #pragma unroll
    for (int kt=0;kt<4;kt++)
      m = fmaxf(m, fmaxf(fmaxf(s[qt][kt][0], s[qt][kt][1]),
                         fmaxf(s[qt][kt][2], s[qt][kt][3])));
    m = fmaxf(m, __shfl_xor(m, 16));
    m = fmaxf(m, __shfl_xor(m, 32));
    float sum = 0.f;
    #pragma unroll
    for (int kt=0;kt<4;kt++)
      #pragma unroll
      for (int r=0;r<4;r++){
        float p = __expf((s[qt][kt][r] - m)*0.25f);   // scores / sqrt(16)
        s[qt][kt][r] = p;
        sum += p;
      }
    sum += __shfl_xor(sum, 16);
    sum += __shfl_xor(sum, 32);
    inv[qt] = 1.f / sum;
    int qq = qt*16 + l15;
    int swz = (qq & 7) << 4;
    #pragma unroll
    for (int kt=0;kt<4;kt++){
      u32 lo = cvtpk(s[qt][kt][0], s[qt][kt][1]);
      u32 hi = cvtpk(s[qt][kt][2], s[qt][kt][3]);
      *(uint2*)(pl + qq*128 + ((kt*32 + grp*8) ^ swz)) = make_uint2(lo, hi);
    }
  }

  // ---- PV ----
  short8 ga[2];
  #pragma unroll
  for (int ks=0;ks<2;ks++)
    ga[ks] = *(const short8*)(gB + l15*64 + ks*32 + grp*8);  // A[d][k]

  u16* yb = yT + (size_t)n*16384 + (size_t)h*16 + grp*4;
  #pragma unroll
  for (int Q=0;Q<4;Q++){
    int qq = Q*16 + l15;
    int swz = (qq & 7) << 4;
    f32x4 acc = Z;
    #pragma unroll
    for (int ks=0;ks<2;ks++){
      short8 pb = *(const short8*)(pl + qq*128 + ((ks*64 + grp*16) ^ swz));
      acc = MFMA(ga[ks], pb, acc);                // D[d][q]
    }
    float iv = inv[Q];
    u32 o0 = cvtpk(acc[0]*iv, acc[1]*iv);
    u32 o1 = cvtpk(acc[2]*iv, acc[3]*iv);
    *(uint2*)(yb + (size_t)qq*256) = make_uint2(o0, o1);     // yT[n][q][h*16+d]
  }
}

// ---------- K4: out = Wo @ y + bo + query via MFMA ----------
__global__ __launch_bounds__(256) void k_out(
    const float* __restrict__ query, const u16* __restrict__ yT,
    const u16* __restrict__ wo_b, const float* __restrict__ bo,
    float* __restrict__ out)
{
  int t = threadIdx.x, lane = t & 63, l15 = lane & 15, q = lane >> 4, w = t >> 6;
  int n = blockIdx.x;
  int mbase = blockIdx.y*256 + w*64;
  const f32x4 Z = {0.f,0.f,0.f,0.f};
  f32x4 acc[4][4];
  #pragma unroll
  for (int mi=0;mi<4;mi++)
    #pragma unroll
    for (int ni=0;ni<4;ni++) acc[mi][ni] = Z;

  #pragma unroll 2
  for (int ks=0; ks<8; ks++){
    int k0 = ks*32;
    short8 a[4], b[4];
    #pragma unroll
    for (int mi=0;mi<4;mi++)
      a[mi] = *(const short8*)(wo_b + (size_t)(mbase + mi*16 + l15)*256 + k0 + q*8);
    #pragma unroll
    for (int ni=0;ni<4;ni++)
      b[ni] = *(const short8*)(yT + (size_t)n*16384 + (size_t)(ni*16 + l15)*256 + k0 + q*8);
    #pragma unroll
    for (int mi=0;mi<4;mi++)
      #pragma unroll
      for (int ni=0;ni<4;ni++) acc[mi][ni] = MFMA(a[mi], b[ni], acc[mi][ni]);
  }

  #pragma unroll
  for (int mi=0;mi<4;mi++)
    #pragma unroll
    for (int r=0;r<4;r++){
      int row = mbase + mi*16 + q*4 + r;
      float bv = bo[row];
      #pragma unroll
      for (int ni=0;ni<4;ni++){
        int col = ni*16 + l15;
        size_t idx = (size_t)n*32768 + (size_t)row*64 + col;
        out[idx] = acc[mi][ni][r] + bv + query[idx];
      }
    }
}

// ---------- launch ----------
extern "C" void kernel_launch(void* const* d_in, const int* in_sizes, int n_in,
                              void* d_out, int out_size, void* d_ws, size_t ws_size,
                              hipStream_t stream)
{
  const float* query = (const float*)d_in[0];
  const float* ctx   = (const float*)d_in[1];
  const float* Wm    = (const float*)d_in[2];
  const float* bm    = (const float*)d_in[3];
  const float* Wg    = (const float*)d_in[4];
  const float* bg    = (const float*)d_in[5];
  const float* Wt    = (const float*)d_in[6];
  const float* bt    = (const float*)d_in[7];
  const float* Wp    = (const float*)d_in[8];
  const float* bp    = (const float*)d_in[9];
  const float* Wo    = (const float*)d_in[10];
  const float* bo    = (const float*)d_in[11];

  u16* wb    = (u16*)d_ws;                 // bf16 weights: 589824 u16
  u16* ctxp  = wb + 589824;                // [1024][512][64] bf16
  u16* theta = ctxp + 33554432;            // [1024][16][64][16] bf16 (x-major)
  u16* phi   = theta + 16777216;           // [1024][16][64][16] bf16 (x-major)
  u16* g     = phi + 16777216;             // [1024][256][64] bf16 (d-major)
  u16* yTb   = ctxp;                       // alias: ctxp dead after k_proj
  float* outp = (float*)d_out;

  hipLaunchKernelGGL(k_prep,   dim3(288),     dim3(256), 0, stream, Wt,Wp,Wg,Wo,Wm, wb);
  hipLaunchKernelGGL(k_posmix, dim3(4096),    dim3(256), 0, stream, ctx, wb+524288, bm, ctxp);
  hipLaunchKernelGGL(k_proj,   dim3(1024,3),  dim3(256), 0, stream,
                     query, ctxp, wb, bt, bp, bg, theta, phi, g);
  hipLaunchKernelGGL(k_attn,   dim3(4096),    dim3(256), 0, stream, theta, phi, g, yTb);
  hipLaunchKernelGGL(k_out,    dim3(1024,2),  dim3(256), 0, stream, query, yTb, wb+393216, bo, outp);
}

// Round 6
// 573.629 us; speedup vs baseline: 1.2692x; 1.0134x over previous
//
#include <hip/hip_runtime.h>
#include <hip/hip_bf16.h>

using u16 = unsigned short;
using u32 = unsigned int;
typedef __attribute__((ext_vector_type(8))) short short8;
typedef __attribute__((ext_vector_type(4))) float f32x4;

// ---------- helpers ----------
__device__ __forceinline__ float bf2f(u16 x){ return __uint_as_float(((u32)x)<<16); }
__device__ __forceinline__ u16 f2bf(float f){
  u32 u = __float_as_uint(f);
  u += 0x7fffu + ((u>>16)&1u);          // round-to-nearest-even
  return (u16)(u>>16);
}
__device__ __forceinline__ u32 cvtpk(float a, float b){
  u32 r;
  asm("v_cvt_pk_bf16_f32 %0, %1, %2" : "=v"(r) : "v"(a), "v"(b));
  return r;                              // lo16 = bf16(a), hi16 = bf16(b), RNE
}
__device__ __forceinline__ short8 pack8(float4 a, float4 b){
  union { short8 s; u32 u[4]; } r;
  r.u[0] = (u32)f2bf(a.x) | ((u32)f2bf(a.y)<<16);
  r.u[1] = (u32)f2bf(a.z) | ((u32)f2bf(a.w)<<16);
  r.u[2] = (u32)f2bf(b.x) | ((u32)f2bf(b.y)<<16);
  r.u[3] = (u32)f2bf(b.z) | ((u32)f2bf(b.w)<<16);
  return r.s;
}
#define MFMA(a,b,c) __builtin_amdgcn_mfma_f32_16x16x32_bf16((a),(b),(c),0,0,0)

// ws layout (u16 offsets): Wt_b 0, Wp_b 131072, Wg_b 262144, Wo_b 393216,
// Wm_b 524288, end 589824. ctxp at 589824. theta/phi/g follow.
// theta/phi are X-MAJOR per head: [n][h][x][16]; g stays d-major [n][c][x].
// yT aliases ctxp (dead after k_proj).

// ---------- K0: weights fp32 -> bf16 ----------
__global__ __launch_bounds__(256) void k_prep(
    const float* __restrict__ Wt, const float* __restrict__ Wp,
    const float* __restrict__ Wg, const float* __restrict__ Wo,
    const float* __restrict__ Wm, u16* __restrict__ wb)
{
  int i8 = (blockIdx.x*256 + threadIdx.x)*8;
  const float* src; int local;
  if      (i8 < 131072){ src = Wt; local = i8; }
  else if (i8 < 262144){ src = Wp; local = i8-131072; }
  else if (i8 < 393216){ src = Wg; local = i8-262144; }
  else if (i8 < 524288){ src = Wo; local = i8-393216; }
  else                 { src = Wm; local = i8-524288; }
  float4 a = *(const float4*)(src+local);
  float4 b = *(const float4*)(src+local+4);
  union { short8 s; uint4 u; } r;
  r.s = pack8(a,b);
  *(uint4*)(wb + i8) = r.u;
}

// ---------- K1: position mixing via MFMA ----------
__global__ __launch_bounds__(256) void k_posmix(
    const float* __restrict__ ctx, const u16* __restrict__ wm_b,
    const float* __restrict__ bm, u16* __restrict__ ctxp)
{
  int lane = threadIdx.x & 63;
  int l15 = lane & 15, q = lane >> 4;
  int wv = (blockIdx.x<<2) + (threadIdx.x>>6);     // 0..16383
  int n = wv >> 4, h = wv & 15;
  const float* cbase = ctx + (size_t)n*32768 + h*2048;   // ctx[n][h*32][0]
  const u16*  wmb   = wm_b + h*4096;
  const f32x4 Z = {0.f,0.f,0.f,0.f};
  f32x4 acc[2][4];
  #pragma unroll
  for (int mi=0;mi<2;mi++)
    #pragma unroll
    for (int ni=0;ni<4;ni++) acc[mi][ni] = Z;

  #pragma unroll
  for (int ks=0; ks<2; ks++){
    short8 a[2], b[4];
    #pragma unroll
    for (int mi=0; mi<2; mi++){
      const float* ap = cbase + (mi*16 + l15)*64 + ks*32 + q*8;
      float4 v0 = *(const float4*)ap;
      float4 v1 = *(const float4*)(ap+4);
      a[mi] = pack8(v0, v1);
    }
    #pragma unroll
    for (int ni=0; ni<4; ni++)
      b[ni] = *(const short8*)(wmb + (ni*16 + l15)*64 + ks*32 + q*8);
    #pragma unroll
    for (int mi=0;mi<2;mi++)
      #pragma unroll
      for (int ni=0;ni<4;ni++) acc[mi][ni] = MFMA(a[mi], b[ni], acc[mi][ni]);
  }

  float bmv[4];
  #pragma unroll
  for (int ni=0;ni<4;ni++) bmv[ni] = bm[h*64 + ni*16 + l15];
  u16* obase = ctxp + (size_t)n*32768 + h*2048;
  #pragma unroll
  for (int mi=0;mi<2;mi++)
    #pragma unroll
    for (int r=0;r<4;r++){
      int row = mi*16 + q*4 + r;                   // d in [0,32)
      #pragma unroll
      for (int ni=0;ni<4;ni++){
        int col = ni*16 + l15;
        float res = cbase[row*64 + col];
        obase[row*64 + col] = f2bf(acc[mi][ni][r] + bmv[ni] + res);
      }
    }
}

// ---------- K2: theta/phi/g projections via MFMA (BK=64 pipelined) ----------
// block = (n, tensor). K=512 in 8 steps of 64, each step = two 32-K chunks.
// Per step: issue next-step staging loads (HBM latency hides under 32 MFMAs)
// -> issue chunk1 weights -> compute chunk0 (16 MFMA) -> issue next-step
// chunk0 weights -> compute chunk1 (16 MFMA) -> write staged data -> ONE
// barrier. Double-buffered LDS (2 steps x 2 chunks).
// tensor==2 (g):      C[o x] = W x S      -> g[n][o][x]   (d-major)
// tensor==0/1:        C[x o] = S^T x W^T  -> T[n][h][x][d] (x-major)
__global__ __launch_bounds__(256) void k_proj(
    const float* __restrict__ query, const u16* __restrict__ ctxp,
    const u16* __restrict__ wb, const float* __restrict__ bt,
    const float* __restrict__ bp, const float* __restrict__ bg,
    u16* __restrict__ theta, u16* __restrict__ phi, u16* __restrict__ g)
{
  __shared__ __align__(16) u16 sb[2][2][64*44 + 16];
  int t = threadIdx.x;
  int lane = t & 63, l15 = lane & 15, q = lane >> 4, w = t >> 6;
  int n = blockIdx.x, tensor = blockIdx.y;
  const u16* W = wb + tensor*131072;
  const float* bias = (tensor==0) ? bt : (tensor==1) ? bp : bg;
  u16* dst = (tensor==0) ? theta : (tensor==1) ? phi : g;
  bool sw = (tensor < 2);          // swapped orientation for theta/phi

  const f32x4 Z = {0.f,0.f,0.f,0.f};
  f32x4 acc[4][4];
  #pragma unroll
  for (int mi=0;mi<4;mi++)
    #pragma unroll
    for (int ni=0;ni<4;ni++) acc[mi][ni] = Z;

  int sc = (t>>4)*2;          // c-pair base (0..30)
  int sx = (t&15)*4;          // x base (0..60)

  const float* qsrc = query + (size_t)n*32768 + (size_t)sc*64 + sx;
  const u16*  csrc = ctxp  + (size_t)n*32768 + (size_t)sc*64 + sx;

  // write one staged 32-K chunk (held in regs) into an LDS chunk buffer
  #define STG_Q(buf, va, vb) { u16* sbn_ = (buf); \
    *(u32*)&sbn_[(sx+0)*44 + sc] = (u32)f2bf((va).x) | ((u32)f2bf((vb).x)<<16); \
    *(u32*)&sbn_[(sx+1)*44 + sc] = (u32)f2bf((va).y) | ((u32)f2bf((vb).y)<<16); \
    *(u32*)&sbn_[(sx+2)*44 + sc] = (u32)f2bf((va).z) | ((u32)f2bf((vb).z)<<16); \
    *(u32*)&sbn_[(sx+3)*44 + sc] = (u32)f2bf((va).w) | ((u32)f2bf((vb).w)<<16); }
  #define STG_C(buf, ua, ub) { u16* sbn_ = (buf); \
    *(u32*)&sbn_[(sx+0)*44 + sc] = ((ua).x & 0xffffu) | (((ub).x & 0xffffu)<<16); \
    *(u32*)&sbn_[(sx+1)*44 + sc] = ((ua).x >> 16)     | ((ub).x & 0xffff0000u); \
    *(u32*)&sbn_[(sx+2)*44 + sc] = ((ua).y & 0xffffu) | (((ub).y & 0xffffu)<<16); \
    *(u32*)&sbn_[(sx+3)*44 + sc] = ((ua).y >> 16)     | ((ub).y & 0xffff0000u); }

  // ---- prologue: stage step 0 (chunks ko=0, ko=32) ----
  if (tensor == 0){
    float4 a0 = *(const float4*)qsrc;
    float4 b0 = *(const float4*)(qsrc + 64);
    float4 a1 = *(const float4*)(qsrc + 32*64);
    float4 b1 = *(const float4*)(qsrc + 32*64 + 64);
    STG_Q(sb[0][0], a0, b0);
    STG_Q(sb[0][1], a1, b1);
  } else {
    uint2 a0 = *(const uint2*)csrc;
    uint2 b0 = *(const uint2*)(csrc + 64);
    uint2 a1 = *(const uint2*)(csrc + 32*64);
    uint2 b1 = *(const uint2*)(csrc + 32*64 + 64);
    STG_C(sb[0][0], a0, b0);
    STG_C(sb[0][1], a1, b1);
  }
  // weights for step0 chunk0
  short8 wf[4];
  #pragma unroll
  for (int mi=0;mi<4;mi++)
    wf[mi] = *(const short8*)(W + (size_t)(w*64 + mi*16 + l15)*512 + q*8);
  __syncthreads();

  #pragma unroll 2
  for (int ks=0; ks<8; ks++){
    int cur = ks & 1;
    int k0 = ks*64;
    bool more = (ks < 7);

    // ---- A: issue next-step staging loads (consumed at end of step) ----
    float4 p0a, p0b, p1a, p1b; uint2 c0a, c0b, c1a, c1b;
    if (more){
      if (tensor == 0){
        const float* s0 = qsrc + (size_t)(k0+64)*64;
        p0a = *(const float4*)s0;
        p0b = *(const float4*)(s0 + 64);
        p1a = *(const float4*)(s0 + 32*64);
        p1b = *(const float4*)(s0 + 32*64 + 64);
      } else {
        const u16* s0 = csrc + (size_t)(k0+64)*64;
        c0a = *(const uint2*)s0;
        c0b = *(const uint2*)(s0 + 64);
        c1a = *(const uint2*)(s0 + 32*64);
        c1b = *(const uint2*)(s0 + 32*64 + 64);
      }
    }
    // ---- B: issue chunk1 weights ----
    short8 wn[4];
    #pragma unroll
    for (int mi=0;mi<4;mi++)
      wn[mi] = *(const short8*)(W + (size_t)(w*64 + mi*16 + l15)*512 + k0+32 + q*8);

    // ---- C: compute chunk0 ----
    {
      const u16* sbc = sb[cur][0];
      short8 sf[4];
      #pragma unroll
      for (int ni=0;ni<4;ni++){
        union { short8 s; uint2 u[2]; } bb;
        int bidx = (ni*16 + l15)*44 + q*8;
        bb.u[0] = *(const uint2*)&sbc[bidx];
        bb.u[1] = *(const uint2*)&sbc[bidx + 4];
        sf[ni] = bb.s;
      }
      __builtin_amdgcn_s_setprio(1);
      if (sw){
        #pragma unroll
        for (int mi=0;mi<4;mi++)
          #pragma unroll
          for (int ni=0;ni<4;ni++) acc[mi][ni] = MFMA(sf[mi], wf[ni], acc[mi][ni]);
      } else {
        #pragma unroll
        for (int mi=0;mi<4;mi++)
          #pragma unroll
          for (int ni=0;ni<4;ni++) acc[mi][ni] = MFMA(wf[mi], sf[ni], acc[mi][ni]);
      }
      __builtin_amdgcn_s_setprio(0);
    }

    // ---- D: issue next-step chunk0 weights (overwrites wf) ----
    if (more){
      #pragma unroll
      for (int mi=0;mi<4;mi++)
        wf[mi] = *(const short8*)(W + (size_t)(w*64 + mi*16 + l15)*512 + k0+64 + q*8);
    }

    // ---- E: compute chunk1 ----
    {
      const u16* sbc = sb[cur][1];
      short8 sf[4];
      #pragma unroll
      for (int ni=0;ni<4;ni++){
        union { short8 s; uint2 u[2]; } bb;
        int bidx = (ni*16 + l15)*44 + q*8;
        bb.u[0] = *(const uint2*)&sbc[bidx];
        bb.u[1] = *(const uint2*)&sbc[bidx + 4];
        sf[ni] = bb.s;
      }
      __builtin_amdgcn_s_setprio(1);
      if (sw){
        #pragma unroll
        for (int mi=0;mi<4;mi++)
          #pragma unroll
          for (int ni=0;ni<4;ni++) acc[mi][ni] = MFMA(sf[mi], wn[ni], acc[mi][ni]);
      } else {
        #pragma unroll
        for (int mi=0;mi<4;mi++)
          #pragma unroll
          for (int ni=0;ni<4;ni++) acc[mi][ni] = MFMA(wn[mi], sf[ni], acc[mi][ni]);
      }
      __builtin_amdgcn_s_setprio(0);
    }

    // ---- F: write staged data for next step + single barrier ----
    if (more){
      if (tensor == 0){
        STG_Q(sb[cur^1][0], p0a, p0b);
        STG_Q(sb[cur^1][1], p1a, p1b);
      } else {
        STG_C(sb[cur^1][0], c0a, c0b);
        STG_C(sb[cur^1][1], c1a, c1b);
      }
      __syncthreads();
    }
  }

  if (!sw){
    // g: rows = o channel, cols = x
    u16* dbase = dst + (size_t)n*16384;
    #pragma unroll
    for (int mi=0;mi<4;mi++)
      #pragma unroll
      for (int r=0;r<4;r++){
        int row = w*64 + mi*16 + q*4 + r;
        float bv = bias[row];
        #pragma unroll
        for (int ni=0;ni<4;ni++){
          int col = ni*16 + l15;
          dbase[row*64 + col] = f2bf(acc[mi][ni][r] + bv);
        }
      }
  } else {
    // theta/phi: acc[i][j][r]: row x = i*16+q*4+r, col o = w*64+j*16+l15
    // -> T[n][h = w*4+j][x][d = l15]
    u16* dbase = dst + (size_t)n*16384 + (size_t)w*4096;
    float bv[4];
    #pragma unroll
    for (int j=0;j<4;j++) bv[j] = bias[w*64 + j*16 + l15];
    #pragma unroll
    for (int i=0;i<4;i++)
      #pragma unroll
      for (int r=0;r<4;r++){
        int x = i*16 + q*4 + r;
        #pragma unroll
        for (int j=0;j<4;j++)
          dbase[j*1024 + x*16 + l15] = f2bf(acc[i][j][r] + bv[j]);
      }
  }
  #undef STG_Q
  #undef STG_C
}

// ---------- K3: attention via MFMA (per n,head per wave) ----------
__global__ __launch_bounds__(256) void k_attn(
    const u16* __restrict__ thetaT, const u16* __restrict__ phiT,
    const u16* __restrict__ g, u16* __restrict__ yT)
{
  __shared__ __align__(16) u16 pbuf[4][4096];     // per-wave 8KB P tile
  int lane = threadIdx.x & 63;
  int w = threadIdx.x >> 6;
  int wv = (blockIdx.x<<2) + w;                   // 0..16383
  int n = wv >> 4, h = wv & 15;
  int l15 = lane & 15, grp = lane >> 4;

  const u16* thB = thetaT + (size_t)n*16384 + h*1024;  // [x][16]
  const u16* phB = phiT   + (size_t)n*16384 + h*1024;  // [x][16]
  const u16* gB  = g      + (size_t)n*16384 + h*1024;  // [16][64] d-major

  const f32x4 Z = {0.f,0.f,0.f,0.f};

  // ---- QK^T ----
  short8 zz; { union{ short8 s; u32 u[4]; } z; z.u[0]=z.u[1]=z.u[2]=z.u[3]=0; zz=z.s; }
  bool real = grp < 2;                            // K-halves 16..31 are zero pad
  short8 aF[4], bF[4];
  #pragma unroll
  for (int kt=0;kt<4;kt++)
    aF[kt] = real ? *(const short8*)(phB + (kt*16+l15)*16 + grp*8) : zz;
  #pragma unroll
  for (int qt=0;qt<4;qt++)
    bF[qt] = real ? *(const short8*)(thB + (qt*16+l15)*16 + grp*8) : zz;

  f32x4 s[4][4];                                  // s[qt][kt]
  #pragma unroll
  for (int qt=0;qt<4;qt++)
    #pragma unroll
    for (int kt=0;kt<4;kt++)
      s[qt][kt] = MFMA(aF[kt], bF[qt], Z);

  // ---- softmax (over k) + pack P -> LDS ----
  char* pl = (char*)pbuf[w];
  float inv[4];
  #pragma unroll
  for (int qt=0;qt<4;qt++){
    float m = s[qt][0][0];
    #pragma unroll
    for (int kt=0;kt<4;kt++)
      m = fmaxf(m, fmaxf(fmaxf(s[qt][kt][0], s[qt][kt][1]),
                         fmaxf(s[qt][kt][2], s[qt][kt][3])));
    m = fmaxf(m, __shfl_xor(m, 16));
    m = fmaxf(m, __shfl_xor(m, 32));
    float sum = 0.f;
    #pragma unroll
    for (int kt=0;kt<4;kt++)
      #pragma unroll
      for (int r=0;r<4;r++){
        float p = __expf((s[qt][kt][r] - m)*0.25f);   // scores / sqrt(16)
        s[qt][kt][r] = p;
        sum += p;
      }
    sum += __shfl_xor(sum, 16);
    sum += __shfl_xor(sum, 32);
    inv[qt] = 1.f / sum;
    int qq = qt*16 + l15;
    int swz = (qq & 7) << 4;
    #pragma unroll
    for (int kt=0;kt<4;kt++){
      u32 lo = cvtpk(s[qt][kt][0], s[qt][kt][1]);
      u32 hi = cvtpk(s[qt][kt][2], s[qt][kt][3]);
      *(uint2*)(pl + qq*128 + ((kt*32 + grp*8) ^ swz)) = make_uint2(lo, hi);
    }
  }

  // ---- PV ----
  short8 ga[2];
  #pragma unroll
  for (int ks=0;ks<2;ks++)
    ga[ks] = *(const short8*)(gB + l15*64 + ks*32 + grp*8);  // A[d][k]

  u16* yb = yT + (size_t)n*16384 + (size_t)h*16 + grp*4;
  #pragma unroll
  for (int Q=0;Q<4;Q++){
    int qq = Q*16 + l15;
    int swz = (qq & 7) << 4;
    f32x4 acc = Z;
    #pragma unroll
    for (int ks=0;ks<2;ks++){
      short8 pb = *(const short8*)(pl + qq*128 + ((ks*64 + grp*16) ^ swz));
      acc = MFMA(ga[ks], pb, acc);                // D[d][q]
    }
    float iv = inv[Q];
    u32 o0 = cvtpk(acc[0]*iv, acc[1]*iv);
    u32 o1 = cvtpk(acc[2]*iv, acc[3]*iv);
    *(uint2*)(yb + (size_t)qq*256) = make_uint2(o0, o1);     // yT[n][q][h*16+d]
  }
}

// ---------- K4: out = Wo @ y + bo + query via MFMA ----------
__global__ __launch_bounds__(256) void k_out(
    const float* __restrict__ query, const u16* __restrict__ yT,
    const u16* __restrict__ wo_b, const float* __restrict__ bo,
    float* __restrict__ out)
{
  int t = threadIdx.x, lane = t & 63, l15 = lane & 15, q = lane >> 4, w = t >> 6;
  int n = blockIdx.x;
  int mbase = blockIdx.y*256 + w*64;
  const f32x4 Z = {0.f,0.f,0.f,0.f};
  f32x4 acc[4][4];
  #pragma unroll
  for (int mi=0;mi<4;mi++)
    #pragma unroll
    for (int ni=0;ni<4;ni++) acc[mi][ni] = Z;

  #pragma unroll 2
  for (int ks=0; ks<8; ks++){
    int k0 = ks*32;
    short8 a[4], b[4];
    #pragma unroll
    for (int mi=0;mi<4;mi++)
      a[mi] = *(const short8*)(wo_b + (size_t)(mbase + mi*16 + l15)*256 + k0 + q*8);
    #pragma unroll
    for (int ni=0;ni<4;ni++)
      b[ni] = *(const short8*)(yT + (size_t)n*16384 + (size_t)(ni*16 + l15)*256 + k0 + q*8);
    #pragma unroll
    for (int mi=0;mi<4;mi++)
      #pragma unroll
      for (int ni=0;ni<4;ni++) acc[mi][ni] = MFMA(a[mi], b[ni], acc[mi][ni]);
  }

  #pragma unroll
  for (int mi=0;mi<4;mi++)
    #pragma unroll
    for (int r=0;r<4;r++){
      int row = mbase + mi*16 + q*4 + r;
      float bv = bo[row];
      #pragma unroll
      for (int ni=0;ni<4;ni++){
        int col = ni*16 + l15;
        size_t idx = (size_t)n*32768 + (size_t)row*64 + col;
        out[idx] = acc[mi][ni][r] + bv + query[idx];
      }
    }
}

// ---------- launch ----------
extern "C" void kernel_launch(void* const* d_in, const int* in_sizes, int n_in,
                              void* d_out, int out_size, void* d_ws, size_t ws_size,
                              hipStream_t stream)
{
  const float* query = (const float*)d_in[0];
  const float* ctx   = (const float*)d_in[1];
  const float* Wm    = (const float*)d_in[2];
  const float* bm    = (const float*)d_in[3];
  const float* Wg    = (const float*)d_in[4];
  const float* bg    = (const float*)d_in[5];
  const float* Wt    = (const float*)d_in[6];
  const float* bt    = (const float*)d_in[7];
  const float* Wp    = (const float*)d_in[8];
  const float* bp    = (const float*)d_in[9];
  const float* Wo    = (const float*)d_in[10];
  const float* bo    = (const float*)d_in[11];

  u16* wb    = (u16*)d_ws;                 // bf16 weights: 589824 u16
  u16* ctxp  = wb + 589824;                // [1024][512][64] bf16
  u16* theta = ctxp + 33554432;            // [1024][16][64][16] bf16 (x-major)
  u16* phi   = theta + 16777216;           // [1024][16][64][16] bf16 (x-major)
  u16* g     = phi + 16777216;             // [1024][256][64] bf16 (d-major)
  u16* yTb   = ctxp;                       // alias: ctxp dead after k_proj
  float* outp = (float*)d_out;

  hipLaunchKernelGGL(k_prep,   dim3(288),     dim3(256), 0, stream, Wt,Wp,Wg,Wo,Wm, wb);
  hipLaunchKernelGGL(k_posmix, dim3(4096),    dim3(256), 0, stream, ctx, wb+524288, bm, ctxp);
  hipLaunchKernelGGL(k_proj,   dim3(1024,3),  dim3(256), 0, stream,
                     query, ctxp, wb, bt, bp, bg, theta, phi, g);
  hipLaunchKernelGGL(k_attn,   dim3(4096),    dim3(256), 0, stream, theta, phi, g, yTb);
  hipLaunchKernelGGL(k_out,    dim3(1024,2),  dim3(256), 0, stream, query, yTb, wb+393216, bo, outp);
}